// Round 1
// baseline (1465.233 us; speedup 1.0000x reference)
//
#include <hip/hip_runtime.h>
#include <math.h>

#define B_ 2
#define H_ 48
#define W_ 48
#define C_ 96
#define D_ 192
#define L_ 2304   // H_*W_
#define K_ 4
#define NS 32     // D_STATE
#define RK 6      // DT_RANK
#define CD 70     // RK + 2*NS

// workspace offsets (floats)
#define BDL (B_*D_*L_)                    // 884736
#define OFF_Z      0
#define OFF_XPRE   (OFF_Z    + BDL)
#define OFF_XHW    (OFF_XPRE + BDL)
#define OFF_XWH    (OFF_XHW  + BDL)
#define OFF_DELTA  (OFF_XWH  + BDL)      // size B*K*D*L
#define OFF_BS     (OFF_DELTA+ B_*K_*D_*L_)
#define OFF_CS     (OFF_BS   + B_*K_*L_*NS)
#define OFF_YS     (OFF_CS   + B_*K_*L_*NS)  // size B*K*L*D, layout (b,k,l,d)
#define OFF_YF     (OFF_YS   + B_*K_*L_*D_)  // size B*L*D

// ---------------- K1: in_proj GEMM  xz[b,pos,e] = sum_c x[b,pos,c]*w[e,c] ----
// writes xpre (b,d,pos) for e<192, z (b,d,pos) for e>=192
__global__ __launch_bounds__(256) void k1_inproj(const float* __restrict__ x,
        const float* __restrict__ w, float* __restrict__ ws) {
    __shared__ __align__(16) float Xs[24*64*4];   // [cq][pos][4]
    int blk = blockIdx.x;
    int b = blk / 36;
    int pos0 = (blk % 36) * 64;
    int tid = threadIdx.x;
    for (int it = 0; it < 24; ++it) {
        int idx = it*256 + tid;
        int p = idx / 96, c = idx % 96;
        float v = x[(size_t)(b*L_ + pos0 + p)*C_ + c];
        Xs[(c>>2)*256 + p*4 + (c&3)] = v;
    }
    __syncthreads();
    int l = tid & 63, eg = tid >> 6;
    float* xpre = ws + OFF_XPRE;
    float* z    = ws + OFF_Z;
    int pos = pos0 + l;
    float4 xr[24];
    #pragma unroll
    for (int q = 0; q < 24; ++q) xr[q] = *(const float4*)&Xs[q*256 + l*4];
    for (int i = 0; i < 96; ++i) {
        int e = eg*96 + i;
        const float4* wp = (const float4*)(w + (size_t)e*96);
        float acc = 0.f;
        #pragma unroll
        for (int q = 0; q < 24; ++q) {
            float4 wv = wp[q];
            acc += xr[q].x*wv.x + xr[q].y*wv.y + xr[q].z*wv.z + xr[q].w*wv.w;
        }
        if (e < D_) xpre[(size_t)(b*D_ + e)*L_ + pos] = acc;
        else        z[(size_t)(b*D_ + (e - D_))*L_ + pos] = acc;
    }
}

// ---------------- K2: depthwise 3x3 conv + bias + SiLU; write hw and wh orders
__global__ __launch_bounds__(256) void k2_conv(const float* __restrict__ cw,
        const float* __restrict__ cb, float* __restrict__ ws) {
    int idx = blockIdx.x*256 + threadIdx.x;   // (b*D + d)*L + pos
    int pos = idx % L_;
    int bd  = idx / L_;
    int d   = bd % D_;
    int hh = pos / W_, w0 = pos % W_;
    const float* xp = ws + OFF_XPRE + (size_t)bd*L_;
    const float* wp = cw + d*9;
    float acc = cb[d];
    #pragma unroll
    for (int kh = 0; kh < 3; ++kh) {
        int ih = hh + kh - 1;
        if (ih < 0 || ih >= H_) continue;
        #pragma unroll
        for (int kw = 0; kw < 3; ++kw) {
            int iw = w0 + kw - 1;
            if (iw < 0 || iw >= W_) continue;
            acc = fmaf(xp[ih*W_ + iw], wp[kh*3 + kw], acc);
        }
    }
    float v = acc / (1.f + __expf(-acc));   // SiLU
    ws[OFF_XHW + (size_t)bd*L_ + pos] = v;
    ws[OFF_XWH + (size_t)bd*L_ + w0*H_ + hh] = v;
}

// ---------------- K3: x_proj matvec + dt_proj + softplus + B/C split ---------
// per (b,k,ltile of 64). deltas -> (b,k,d,l); Bs/Cs -> (b,k,l,n)
__global__ __launch_bounds__(256) void k3_xproj(const float* __restrict__ xpw,
        const float* __restrict__ dtw, const float* __restrict__ dtb,
        float* __restrict__ ws) {
    __shared__ __align__(16) float Xs[48*64*4];   // xs tile [dq][l][4]
    __shared__ float xd[CD*65];                    // x_dbl tile [c][l], pad 65
    int blk = blockIdx.x;
    int b  = blk / (K_*36);
    int k  = (blk / 36) % K_;
    int l0 = (blk % 36) * 64;
    int tid = threadIdx.x;
    const float* src = ws + ((k & 1) ? OFF_XWH : OFF_XHW);
    bool flip = (k >= 2);
    for (int it = 0; it < 48; ++it) {
        int idx = it*256 + tid;
        int d = idx >> 6, l = idx & 63;
        int pos = flip ? (L_ - 1 - (l0 + l)) : (l0 + l);
        Xs[(d>>2)*256 + l*4 + (d&3)] = src[(size_t)(b*D_ + d)*L_ + pos];
    }
    __syncthreads();
    int l = tid & 63, cg = tid >> 6;
    {
        float acc[18];
        #pragma unroll
        for (int i = 0; i < 18; ++i) acc[i] = 0.f;
        for (int half = 0; half < 2; ++half) {
            float4 xr[24];
            #pragma unroll
            for (int q = 0; q < 24; ++q) xr[q] = *(const float4*)&Xs[(half*24+q)*256 + l*4];
            for (int i = 0; i < 18; ++i) {
                int c = cg*18 + i;
                if (c < CD) {
                    const float4* wp = (const float4*)(xpw + ((size_t)k*CD + c)*D_) + half*24;
                    #pragma unroll
                    for (int q = 0; q < 24; ++q) {
                        float4 wv = wp[q];
                        acc[i] += xr[q].x*wv.x + xr[q].y*wv.y + xr[q].z*wv.z + xr[q].w*wv.w;
                    }
                }
            }
        }
        for (int i = 0; i < 18; ++i) {
            int c = cg*18 + i;
            if (c < CD) xd[c*65 + l] = acc[i];
        }
    }
    __syncthreads();
    {   // dt_proj + softplus -> deltas (b,k,d,l)
        float r[6];
        #pragma unroll
        for (int rr = 0; rr < 6; ++rr) r[rr] = xd[rr*65 + l];
        float* dout = ws + OFF_DELTA + (size_t)(b*K_ + k)*D_*L_;
        int dg = tid >> 6;
        for (int i = 0; i < 48; ++i) {
            int d = dg*48 + i;
            const float* wdt = dtw + ((size_t)k*D_ + d)*6;
            float acc = dtb[k*D_ + d];
            #pragma unroll
            for (int rr = 0; rr < 6; ++rr) acc = fmaf(r[rr], wdt[rr], acc);
            float sp = fmaxf(acc, 0.f) + log1pf(__expf(-fabsf(acc)));
            dout[(size_t)d*L_ + l0 + l] = sp;
        }
    }
    {   // Bs/Cs -> (b,k,l,n)
        float* Bsp = ws + OFF_BS + ((size_t)(b*K_ + k)*L_ + l0)*NS;
        float* Csp = ws + OFF_CS + ((size_t)(b*K_ + k)*L_ + l0)*NS;
        int n = tid & 31, lq = tid >> 5;
        for (int it = 0; it < 8; ++it) {
            int ll = it*8 + lq;
            Bsp[(size_t)ll*NS + n] = xd[(RK + n)*65 + ll];
            Csp[(size_t)ll*NS + n] = xd[(RK + NS + n)*65 + ll];
        }
    }
}

// ---------------- K4: selective scan. half-wave per (b,k,d) chain, lane=state
__global__ __launch_bounds__(64) void k4_scan(const float* __restrict__ Alogs,
        const float* __restrict__ Dsp, float* __restrict__ ws) {
    int blk = blockIdx.x;            // 768 = 8 bk * 96
    int bk = blk / 96;
    int b = bk >> 2, k = bk & 3;
    int half = (threadIdx.x >> 5) & 1;
    int n = threadIdx.x & 31;
    int d = (blk % 96)*2 + half;
    float a = -__expf(Alogs[((size_t)k*D_ + d)*NS + n]);
    float dcoef = Dsp[k*D_ + d];
    const float* dptr = ws + OFF_DELTA + ((size_t)bk*D_ + d)*L_;
    const float* uptr = ws + ((k & 1) ? OFF_XWH : OFF_XHW) + (size_t)(b*D_ + d)*L_;
    const float* Bsp = ws + OFF_BS + (size_t)bk*L_*NS;
    const float* Csp = ws + OFF_CS + (size_t)bk*L_*NS;
    float* ysp = ws + OFF_YS + (size_t)bk*L_*D_ + d;
    bool flip = (k >= 2);
    float h = 0.f;
    #pragma unroll 4
    for (int l = 0; l < L_; ++l) {
        float delta = dptr[l];
        float u = uptr[flip ? (L_ - 1 - l) : l];
        float bn = Bsp[l*NS + n];
        float cn = Csp[l*NS + n];
        float dA = __expf(delta * a);
        h = fmaf(h, dA, delta*u*bn);
        float y = h * cn;
        y += __shfl_xor(y, 16);
        y += __shfl_xor(y, 8);
        y += __shfl_xor(y, 4);
        y += __shfl_xor(y, 2);
        y += __shfl_xor(y, 1);
        if (n == 0) ysp[(size_t)l*D_] = fmaf(dcoef, u, y);
    }
}

// ---------------- K5: merge 4 directions + LayerNorm + SiLU(z) gate ----------
__global__ __launch_bounds__(192) void k5_combine(const float* __restrict__ lnw,
        const float* __restrict__ lnb, float* __restrict__ ws) {
    int bp = blockIdx.x;           // b*L + pos
    int b = bp / L_, pos = bp % L_;
    int d = threadIdx.x;
    int hh = pos / W_, w0 = pos % W_;
    int poswh = w0*H_ + hh;
    const float* ys = ws + OFF_YS + (size_t)b*K_*L_*D_;
    float y = ys[(size_t)(0*L_ + pos)*D_ + d]
            + ys[(size_t)(2*L_ + (L_ - 1 - pos))*D_ + d]
            + ys[(size_t)(1*L_ + poswh)*D_ + d]
            + ys[(size_t)(3*L_ + (L_ - 1 - poswh))*D_ + d];
    float s = y, ss = y*y;
    #pragma unroll
    for (int m = 32; m >= 1; m >>= 1) {
        s  += __shfl_xor(s, m);
        ss += __shfl_xor(ss, m);
    }
    __shared__ float red[2][4];
    int wv = threadIdx.x >> 6;
    if ((threadIdx.x & 63) == 0) { red[0][wv] = s; red[1][wv] = ss; }
    __syncthreads();
    float su = red[0][0] + red[0][1] + red[0][2];
    float sq = red[1][0] + red[1][1] + red[1][2];
    float mu  = su * (1.f/192.f);
    float var = sq * (1.f/192.f) - mu*mu;
    float rs  = rsqrtf(var + 1e-5f);
    float yn = (y - mu)*rs*lnw[d] + lnb[d];
    float zv = ws[OFF_Z + (size_t)(b*D_ + d)*L_ + pos];
    float sz = zv / (1.f + __expf(-zv));
    ws[OFF_YF + (size_t)(b*L_ + pos)*D_ + d] = yn * sz;
}

// ---------------- K6: out_proj GEMM + residual -------------------------------
__global__ __launch_bounds__(256) void k6_outproj(const float* __restrict__ w,
        const float* __restrict__ xin, float* __restrict__ out,
        const float* __restrict__ ws) {
    __shared__ __align__(16) float Ys[48*64*4];   // [dq][pos][4]
    int blk = blockIdx.x;
    int b = blk / 36;
    int pos0 = (blk % 36) * 64;
    int tid = threadIdx.x;
    const float* yf = ws + OFF_YF;
    for (int it = 0; it < 48; ++it) {
        int idx = it*256 + tid;
        int p = idx / 192, dd = idx % 192;
        Ys[(dd>>2)*256 + p*4 + (dd&3)] = yf[(size_t)(b*L_ + pos0 + p)*D_ + dd];
    }
    __syncthreads();
    int l = tid & 63, cg = tid >> 6;
    float acc[24];
    #pragma unroll
    for (int i = 0; i < 24; ++i) acc[i] = 0.f;
    for (int half = 0; half < 2; ++half) {
        float4 yr[24];
        #pragma unroll
        for (int q = 0; q < 24; ++q) yr[q] = *(const float4*)&Ys[(half*24+q)*256 + l*4];
        for (int i = 0; i < 24; ++i) {
            int c = cg*24 + i;
            const float4* wp = (const float4*)(w + (size_t)c*D_) + half*24;
            #pragma unroll
            for (int q = 0; q < 24; ++q) {
                float4 wv = wp[q];
                acc[i] += yr[q].x*wv.x + yr[q].y*wv.y + yr[q].z*wv.z + yr[q].w*wv.w;
            }
        }
    }
    int pos = pos0 + l;
    for (int i = 0; i < 24; ++i) {
        int c = cg*24 + i;
        size_t o = (size_t)(b*L_ + pos)*C_ + c;
        out[o] = xin[o] + acc[i];
    }
}

extern "C" void kernel_launch(void* const* d_in, const int* in_sizes, int n_in,
                              void* d_out, int out_size, void* d_ws, size_t ws_size,
                              hipStream_t stream) {
    const float* x        = (const float*)d_in[0];
    const float* in_proj  = (const float*)d_in[1];
    const float* conv_w   = (const float*)d_in[2];
    const float* conv_b   = (const float*)d_in[3];
    const float* x_proj_w = (const float*)d_in[4];
    const float* dt_w     = (const float*)d_in[5];
    const float* dt_b     = (const float*)d_in[6];
    const float* A_logs   = (const float*)d_in[7];
    const float* Ds       = (const float*)d_in[8];
    const float* ln_w     = (const float*)d_in[9];
    const float* ln_b     = (const float*)d_in[10];
    const float* out_w    = (const float*)d_in[11];
    float* out = (float*)d_out;
    float* ws  = (float*)d_ws;

    k1_inproj <<<72,   256, 0, stream>>>(x, in_proj, ws);
    k2_conv   <<<3456, 256, 0, stream>>>(conv_w, conv_b, ws);
    k3_xproj  <<<288,  256, 0, stream>>>(x_proj_w, dt_w, dt_b, ws);
    k4_scan   <<<768,  64,  0, stream>>>(A_logs, Ds, ws);
    k5_combine<<<4608, 192, 0, stream>>>(ln_w, ln_b, ws);
    k6_outproj<<<72,   256, 0, stream>>>(out_w, x, out, ws);
}

// Round 2
// 500.735 us; speedup vs baseline: 2.9262x; 2.9262x over previous
//
#include <hip/hip_runtime.h>
#include <math.h>

#define B_ 2
#define H_ 48
#define W_ 48
#define C_ 96
#define D_ 192
#define L_ 2304   // H_*W_
#define K_ 4
#define NS 32     // D_STATE
#define RK 6      // DT_RANK
#define CD 70     // RK + 2*NS

#define NC 8          // scan chunks
#define CL (L_/NC)    // 288 steps per chunk
#define NCH (B_*K_*D_)// 1536 chains

// workspace offsets (floats)
#define BDL (B_*D_*L_)                    // 884736
#define OFF_Z      0
#define OFF_XPRE   (OFF_Z    + BDL)
#define OFF_XHW    (OFF_XPRE + BDL)
#define OFF_XWH    (OFF_XHW  + BDL)
#define OFF_DELTA  (OFF_XWH  + BDL)      // size B*K*D*L
#define OFF_BS     (OFF_DELTA+ B_*K_*D_*L_)
#define OFF_CS     (OFF_BS   + B_*K_*L_*NS)
#define OFF_YS     (OFF_CS   + B_*K_*L_*NS)  // size B*K*L*D, layout (b,k,l,d)
#define OFF_YF     (OFF_YS   + B_*K_*L_*D_)  // size B*L*D

// scan scratch: reuse XPRE (dead after k2) and YF (dead until k5)
#define OFF_P      OFF_XPRE                    // NCH*NC*NS = 393216
#define OFF_HF     (OFF_XPRE + NCH*NC*NS)      // 393216 (786432 <= 884736 OK)
#define OFF_H0     OFF_YF                      // 393216 <= 884736 OK

// ---------------- K1: in_proj GEMM  xz[b,pos,e] = sum_c x[b,pos,c]*w[e,c] ----
// grid 288 = b(2) * postile(36) * eslice(4); writes xpre / z in (b,d,pos)
__global__ __launch_bounds__(256) void k1_inproj(const float* __restrict__ x,
        const float* __restrict__ w, float* __restrict__ ws) {
    __shared__ __align__(16) float Xs[24*64*4];   // [cq][pos][4]
    int blk = blockIdx.x;
    int b = blk / 144;
    int rem = blk % 144;
    int pos0 = (rem >> 2) * 64;
    int es = rem & 3;
    int tid = threadIdx.x;
    for (int it = 0; it < 24; ++it) {
        int idx = it*256 + tid;
        int p = idx / 96, c = idx % 96;
        Xs[(c>>2)*256 + p*4 + (c&3)] = x[(size_t)(b*L_ + pos0 + p)*C_ + c];
    }
    __syncthreads();
    int l = tid & 63, eg = tid >> 6;
    float* xpre = ws + OFF_XPRE;   // NOTE: scratch-aliased later, but k2 reads it first
    float* z    = ws + OFF_Z;
    int pos = pos0 + l;
    float4 xr[24];
    #pragma unroll
    for (int q = 0; q < 24; ++q) xr[q] = *(const float4*)&Xs[q*256 + l*4];
    for (int i = 0; i < 24; ++i) {
        int e = es*96 + eg*24 + i;
        const float4* wp = (const float4*)(w + (size_t)e*96);
        float acc = 0.f;
        #pragma unroll
        for (int q = 0; q < 24; ++q) {
            float4 wv = wp[q];
            acc += xr[q].x*wv.x + xr[q].y*wv.y + xr[q].z*wv.z + xr[q].w*wv.w;
        }
        if (e < D_) xpre[(size_t)(b*D_ + e)*L_ + pos] = acc;
        else        z[(size_t)(b*D_ + (e - D_))*L_ + pos] = acc;
    }
}

// ---------------- K2: depthwise 3x3 conv + bias + SiLU; write hw and wh orders
__global__ __launch_bounds__(256) void k2_conv(const float* __restrict__ cw,
        const float* __restrict__ cb, float* __restrict__ ws) {
    int idx = blockIdx.x*256 + threadIdx.x;   // (b*D + d)*L + pos
    int pos = idx % L_;
    int bd  = idx / L_;
    int d   = bd % D_;
    int hh = pos / W_, w0 = pos % W_;
    const float* xp = ws + OFF_XPRE + (size_t)bd*L_;
    const float* wp = cw + d*9;
    float acc = cb[d];
    #pragma unroll
    for (int kh = 0; kh < 3; ++kh) {
        int ih = hh + kh - 1;
        if (ih < 0 || ih >= H_) continue;
        #pragma unroll
        for (int kw = 0; kw < 3; ++kw) {
            int iw = w0 + kw - 1;
            if (iw < 0 || iw >= W_) continue;
            acc = fmaf(xp[ih*W_ + iw], wp[kh*3 + kw], acc);
        }
    }
    float v = acc / (1.f + __expf(-acc));   // SiLU
    ws[OFF_XHW + (size_t)bd*L_ + pos] = v;
    ws[OFF_XWH + (size_t)bd*L_ + w0*H_ + hh] = v;
}

// ---------------- K3: x_proj matvec + dt_proj + softplus + B/C split ---------
// per (b,k,ltile of 64). deltas -> (b,k,d,l); Bs/Cs -> (b,k,l,n)
__global__ __launch_bounds__(256) void k3_xproj(const float* __restrict__ xpw,
        const float* __restrict__ dtw, const float* __restrict__ dtb,
        float* __restrict__ ws) {
    __shared__ __align__(16) float Xs[48*64*4];   // xs tile [dq][l][4]
    __shared__ float xd[CD*65];                    // x_dbl tile [c][l], pad 65
    int blk = blockIdx.x;
    int b  = blk / (K_*36);
    int k  = (blk / 36) % K_;
    int l0 = (blk % 36) * 64;
    int tid = threadIdx.x;
    const float* src = ws + ((k & 1) ? OFF_XWH : OFF_XHW);
    bool flip = (k >= 2);
    for (int it = 0; it < 48; ++it) {
        int idx = it*256 + tid;
        int d = idx >> 6, l = idx & 63;
        int pos = flip ? (L_ - 1 - (l0 + l)) : (l0 + l);
        Xs[(d>>2)*256 + l*4 + (d&3)] = src[(size_t)(b*D_ + d)*L_ + pos];
    }
    __syncthreads();
    int l = tid & 63, cg = tid >> 6;
    {
        float acc[18];
        #pragma unroll
        for (int i = 0; i < 18; ++i) acc[i] = 0.f;
        for (int half = 0; half < 2; ++half) {
            float4 xr[24];
            #pragma unroll
            for (int q = 0; q < 24; ++q) xr[q] = *(const float4*)&Xs[(half*24+q)*256 + l*4];
            for (int i = 0; i < 18; ++i) {
                int c = cg*18 + i;
                if (c < CD) {
                    const float4* wp = (const float4*)(xpw + ((size_t)k*CD + c)*D_) + half*24;
                    #pragma unroll
                    for (int q = 0; q < 24; ++q) {
                        float4 wv = wp[q];
                        acc[i] += xr[q].x*wv.x + xr[q].y*wv.y + xr[q].z*wv.z + xr[q].w*wv.w;
                    }
                }
            }
        }
        for (int i = 0; i < 18; ++i) {
            int c = cg*18 + i;
            if (c < CD) xd[c*65 + l] = acc[i];
        }
    }
    __syncthreads();
    {   // dt_proj + softplus -> deltas (b,k,d,l)
        float r[6];
        #pragma unroll
        for (int rr = 0; rr < 6; ++rr) r[rr] = xd[rr*65 + l];
        float* dout = ws + OFF_DELTA + (size_t)(b*K_ + k)*D_*L_;
        int dg = tid >> 6;
        for (int i = 0; i < 48; ++i) {
            int d = dg*48 + i;
            const float* wdt = dtw + ((size_t)k*D_ + d)*6;
            float acc = dtb[k*D_ + d];
            #pragma unroll
            for (int rr = 0; rr < 6; ++rr) acc = fmaf(r[rr], wdt[rr], acc);
            float sp = fmaxf(acc, 0.f) + log1pf(__expf(-fabsf(acc)));
            dout[(size_t)d*L_ + l0 + l] = sp;
        }
    }
    {   // Bs/Cs -> (b,k,l,n)
        float* Bsp = ws + OFF_BS + ((size_t)(b*K_ + k)*L_ + l0)*NS;
        float* Csp = ws + OFF_CS + ((size_t)(b*K_ + k)*L_ + l0)*NS;
        int n = tid & 31, lq = tid >> 5;
        for (int it = 0; it < 8; ++it) {
            int ll = it*8 + lq;
            Bsp[(size_t)ll*NS + n] = xd[(RK + n)*65 + ll];
            Csp[(size_t)ll*NS + n] = xd[(RK + NS + n)*65 + ll];
        }
    }
}

// ---------------- K4a: chunked scan pass 1 — local state + chunk dA product --
// task = chain*NC + c; half-wave (32 lanes = states) per task; 2 tasks/block
__global__ __launch_bounds__(64) void k4a_local(const float* __restrict__ Alogs,
        float* __restrict__ ws) {
    int task = blockIdx.x*2 + (threadIdx.x >> 5);
    int n = threadIdx.x & 31;
    int c = task & (NC-1);
    int chain = task >> 3;             // (b*K+k)*D + d
    int d = chain % D_;
    int bk = chain / D_;
    int b = bk >> 2, k = bk & 3;
    float a = -__expf(Alogs[((size_t)k*D_ + d)*NS + n]);
    const float* dptr = ws + OFF_DELTA + (size_t)chain*L_ + c*CL;
    const float* ubase = ws + ((k & 1) ? OFF_XWH : OFF_XHW) + (size_t)(b*D_ + d)*L_;
    const float* Bsp = ws + OFF_BS + ((size_t)bk*L_ + c*CL)*NS;
    bool flip = (k >= 2);
    float h = 0.f, P = 1.f;
    #pragma unroll 4
    for (int l = 0; l < CL; ++l) {
        int gl = c*CL + l;
        float delta = dptr[l];
        float u = ubase[flip ? (L_ - 1 - gl) : gl];
        float bn = Bsp[l*NS + n];
        float dA = __expf(delta * a);
        h = fmaf(h, dA, delta*u*bn);
        P *= dA;
    }
    ws[OFF_P  + (size_t)task*NS + n] = P;
    ws[OFF_HF + (size_t)task*NS + n] = h;
}

// ---------------- K4b: per-chain serial combine over chunks ------------------
__global__ __launch_bounds__(256) void k4b_combine(float* __restrict__ ws) {
    int chain = blockIdx.x*8 + (threadIdx.x >> 5);
    int n = threadIdx.x & 31;
    size_t base = (size_t)chain*NC;
    float h0 = 0.f;
    #pragma unroll
    for (int c = 0; c < NC; ++c) {
        ws[OFF_H0 + (base + c)*NS + n] = h0;
        float P  = ws[OFF_P  + (base + c)*NS + n];
        float hF = ws[OFF_HF + (base + c)*NS + n];
        h0 = fmaf(h0, P, hF);
    }
}

// ---------------- K4c: chunked scan pass 2 — full scan + y, from h0 ----------
__global__ __launch_bounds__(64) void k4c_scan(const float* __restrict__ Alogs,
        const float* __restrict__ Dsp, float* __restrict__ ws) {
    int task = blockIdx.x*2 + (threadIdx.x >> 5);
    int n = threadIdx.x & 31;
    int c = task & (NC-1);
    int chain = task >> 3;
    int d = chain % D_;
    int bk = chain / D_;
    int b = bk >> 2, k = bk & 3;
    float a = -__expf(Alogs[((size_t)k*D_ + d)*NS + n]);
    float dcoef = Dsp[k*D_ + d];
    const float* dptr = ws + OFF_DELTA + (size_t)chain*L_ + c*CL;
    const float* ubase = ws + ((k & 1) ? OFF_XWH : OFF_XHW) + (size_t)(b*D_ + d)*L_;
    const float* Bsp = ws + OFF_BS + ((size_t)bk*L_ + c*CL)*NS;
    const float* Csp = ws + OFF_CS + ((size_t)bk*L_ + c*CL)*NS;
    float* ysp = ws + OFF_YS + ((size_t)bk*L_ + c*CL)*D_ + d;
    bool flip = (k >= 2);
    float h = ws[OFF_H0 + (size_t)task*NS + n];
    #pragma unroll 4
    for (int l = 0; l < CL; ++l) {
        int gl = c*CL + l;
        float delta = dptr[l];
        float u = ubase[flip ? (L_ - 1 - gl) : gl];
        float bn = Bsp[l*NS + n];
        float cn = Csp[l*NS + n];
        float dA = __expf(delta * a);
        h = fmaf(h, dA, delta*u*bn);
        float y = h * cn;
        y += __shfl_xor(y, 16);
        y += __shfl_xor(y, 8);
        y += __shfl_xor(y, 4);
        y += __shfl_xor(y, 2);
        y += __shfl_xor(y, 1);
        if (n == 0) ysp[(size_t)l*D_] = fmaf(dcoef, u, y);
    }
}

// ---------------- K5: merge 4 directions + LayerNorm + SiLU(z) gate ----------
__global__ __launch_bounds__(192) void k5_combine(const float* __restrict__ lnw,
        const float* __restrict__ lnb, float* __restrict__ ws) {
    int bp = blockIdx.x;           // b*L + pos
    int b = bp / L_, pos = bp % L_;
    int d = threadIdx.x;
    int hh = pos / W_, w0 = pos % W_;
    int poswh = w0*H_ + hh;
    const float* ys = ws + OFF_YS + (size_t)b*K_*L_*D_;
    float y = ys[(size_t)(0*L_ + pos)*D_ + d]
            + ys[(size_t)(2*L_ + (L_ - 1 - pos))*D_ + d]
            + ys[(size_t)(1*L_ + poswh)*D_ + d]
            + ys[(size_t)(3*L_ + (L_ - 1 - poswh))*D_ + d];
    float s = y, ss = y*y;
    #pragma unroll
    for (int m = 32; m >= 1; m >>= 1) {
        s  += __shfl_xor(s, m);
        ss += __shfl_xor(ss, m);
    }
    __shared__ float red[2][4];
    int wv = threadIdx.x >> 6;
    if ((threadIdx.x & 63) == 0) { red[0][wv] = s; red[1][wv] = ss; }
    __syncthreads();
    float su = red[0][0] + red[0][1] + red[0][2];
    float sq = red[1][0] + red[1][1] + red[1][2];
    float mu  = su * (1.f/192.f);
    float var = sq * (1.f/192.f) - mu*mu;
    float rs  = rsqrtf(var + 1e-5f);
    float yn = (y - mu)*rs*lnw[d] + lnb[d];
    float zv = ws[OFF_Z + (size_t)(b*D_ + d)*L_ + pos];
    float sz = zv / (1.f + __expf(-zv));
    ws[OFF_YF + (size_t)(b*L_ + pos)*D_ + d] = yn * sz;
}

// ---------------- K6: out_proj GEMM + residual -------------------------------
__global__ __launch_bounds__(256) void k6_outproj(const float* __restrict__ w,
        const float* __restrict__ xin, float* __restrict__ out,
        const float* __restrict__ ws) {
    __shared__ __align__(16) float Ys[48*64*4];   // [dq][pos][4]
    int blk = blockIdx.x;
    int b = blk / 36;
    int pos0 = (blk % 36) * 64;
    int tid = threadIdx.x;
    const float* yf = ws + OFF_YF;
    for (int it = 0; it < 48; ++it) {
        int idx = it*256 + tid;
        int p = idx / 192, dd = idx % 192;
        Ys[(dd>>2)*256 + p*4 + (dd&3)] = yf[(size_t)(b*L_ + pos0 + p)*D_ + dd];
    }
    __syncthreads();
    int l = tid & 63, cg = tid >> 6;
    float acc[24];
    #pragma unroll
    for (int i = 0; i < 24; ++i) acc[i] = 0.f;
    for (int half = 0; half < 2; ++half) {
        float4 yr[24];
        #pragma unroll
        for (int q = 0; q < 24; ++q) yr[q] = *(const float4*)&Ys[(half*24+q)*256 + l*4];
        for (int i = 0; i < 24; ++i) {
            int c = cg*24 + i;
            const float4* wp = (const float4*)(w + (size_t)c*D_) + half*24;
            #pragma unroll
            for (int q = 0; q < 24; ++q) {
                float4 wv = wp[q];
                acc[i] += yr[q].x*wv.x + yr[q].y*wv.y + yr[q].z*wv.z + yr[q].w*wv.w;
            }
        }
    }
    int pos = pos0 + l;
    for (int i = 0; i < 24; ++i) {
        int c = cg*24 + i;
        size_t o = (size_t)(b*L_ + pos)*C_ + c;
        out[o] = xin[o] + acc[i];
    }
}

extern "C" void kernel_launch(void* const* d_in, const int* in_sizes, int n_in,
                              void* d_out, int out_size, void* d_ws, size_t ws_size,
                              hipStream_t stream) {
    const float* x        = (const float*)d_in[0];
    const float* in_proj  = (const float*)d_in[1];
    const float* conv_w   = (const float*)d_in[2];
    const float* conv_b   = (const float*)d_in[3];
    const float* x_proj_w = (const float*)d_in[4];
    const float* dt_w     = (const float*)d_in[5];
    const float* dt_b     = (const float*)d_in[6];
    const float* A_logs   = (const float*)d_in[7];
    const float* Ds       = (const float*)d_in[8];
    const float* ln_w     = (const float*)d_in[9];
    const float* ln_b     = (const float*)d_in[10];
    const float* out_w    = (const float*)d_in[11];
    float* out = (float*)d_out;
    float* ws  = (float*)d_ws;

    k1_inproj <<<288,  256, 0, stream>>>(x, in_proj, ws);
    k2_conv   <<<3456, 256, 0, stream>>>(conv_w, conv_b, ws);
    k3_xproj  <<<288,  256, 0, stream>>>(x_proj_w, dt_w, dt_b, ws);
    k4a_local <<<NCH*NC/2, 64, 0, stream>>>(A_logs, ws);
    k4b_combine<<<NCH/8, 256, 0, stream>>>(ws);
    k4c_scan  <<<NCH*NC/2, 64, 0, stream>>>(A_logs, Ds, ws);
    k5_combine<<<4608, 192, 0, stream>>>(ln_w, ln_b, ws);
    k6_outproj<<<72,   256, 0, stream>>>(out_w, x, out, ws);
}

// Round 3
// 372.724 us; speedup vs baseline: 3.9311x; 1.3434x over previous
//
#include <hip/hip_runtime.h>
#include <math.h>

#define B_ 2
#define H_ 48
#define W_ 48
#define C_ 96
#define D_ 192
#define L_ 2304   // H_*W_
#define K_ 4
#define NS 32     // D_STATE
#define RK 6      // DT_RANK
#define CD 70     // RK + 2*NS

#define NC 16         // scan chunks
#define CL (L_/NC)    // 144 steps per chunk
#define NCH (B_*K_*D_)// 1536 chains

// workspace offsets (floats)
#define BDL (B_*D_*L_)                    // 884736
#define OFF_Z      0                      // z stored (b, l, d) !
#define OFF_XPRE   (OFF_Z    + BDL)
#define OFF_XHW    (OFF_XPRE + BDL)
#define OFF_XWH    (OFF_XHW  + BDL)
#define OFF_DELTA  (OFF_XWH  + BDL)      // size B*K*D*L
#define OFF_BS     (OFF_DELTA+ B_*K_*D_*L_)
#define OFF_CS     (OFF_BS   + B_*K_*L_*NS)
#define OFF_YS     (OFF_CS   + B_*K_*L_*NS)  // size B*K*L*D, layout (b,k,l,d)
#define OFF_YF     (OFF_YS   + B_*K_*L_*D_)  // size B*L*D

// scan scratch (NC=16: each array = NCH*NC*NS = 786432 floats)
// P  -> XPRE (dead after k2, 884736 >= 786432)
// HF -> YS head (k4c overwrites AFTER k4b consumed it)
// H0 -> YF (dead until k5; k4c reads it before writing YS)
#define OFF_P      OFF_XPRE
#define OFF_HF     OFF_YS
#define OFF_H0     OFF_YF

// ---------------- K1: in_proj GEMM  xz[b,pos,e] = sum_c x[b,pos,c]*w[e,c] ----
// grid 288 = b(2) * postile(36) * eslice(4)
// e<192 -> xpre (b,d,pos);  e>=192 -> z (b,pos,d)  [coalesced for k5]
__global__ __launch_bounds__(256) void k1_inproj(const float* __restrict__ x,
        const float* __restrict__ w, float* __restrict__ ws) {
    __shared__ __align__(16) float Xs[24*64*4];   // [cq][pos][4]
    int blk = blockIdx.x;
    int b = blk / 144;
    int rem = blk % 144;
    int pos0 = (rem >> 2) * 64;
    int es = rem & 3;
    int tid = threadIdx.x;
    for (int it = 0; it < 24; ++it) {
        int idx = it*256 + tid;
        int p = idx / 96, c = idx % 96;
        Xs[(c>>2)*256 + p*4 + (c&3)] = x[(size_t)(b*L_ + pos0 + p)*C_ + c];
    }
    __syncthreads();
    int l = tid & 63, eg = tid >> 6;
    int pos = pos0 + l;
    float4 xr[24];
    #pragma unroll
    for (int q = 0; q < 24; ++q) xr[q] = *(const float4*)&Xs[q*256 + l*4];
    float acc[24];
    for (int i = 0; i < 24; ++i) {
        int e = es*96 + eg*24 + i;
        const float4* wp = (const float4*)(w + (size_t)e*96);
        float a = 0.f;
        #pragma unroll
        for (int q = 0; q < 24; ++q) {
            float4 wv = wp[q];
            a += xr[q].x*wv.x + xr[q].y*wv.y + xr[q].z*wv.z + xr[q].w*wv.w;
        }
        acc[i] = a;
    }
    if (es < 2) {
        float* xpre = ws + OFF_XPRE;
        for (int i = 0; i < 24; ++i) {
            int e = es*96 + eg*24 + i;
            xpre[(size_t)(b*D_ + e)*L_ + pos] = acc[i];
        }
    } else {
        float* zp = ws + OFF_Z + (size_t)(b*L_ + pos)*D_ + (es-2)*96 + eg*24;
        #pragma unroll
        for (int q = 0; q < 6; ++q)
            *(float4*)&zp[q*4] = make_float4(acc[q*4], acc[q*4+1], acc[q*4+2], acc[q*4+3]);
    }
}

// ---------------- K2: depthwise 3x3 conv + SiLU; one block per (b,d) image ---
// both XHW and XWH writes coalesced (XWH via LDS transpose)
__global__ __launch_bounds__(256) void k2_conv(const float* __restrict__ cw,
        const float* __restrict__ cb, float* __restrict__ ws) {
    __shared__ float img[L_];
    __shared__ float res[L_];
    int bd = blockIdx.x;               // 384
    int d = bd % D_;
    int tid = threadIdx.x;
    const float* xp = ws + OFF_XPRE + (size_t)bd*L_;
    for (int i = 0; i < 9; ++i) img[i*256 + tid] = xp[i*256 + tid];
    float wr[9];
    #pragma unroll
    for (int j = 0; j < 9; ++j) wr[j] = cw[d*9 + j];
    float bias = cb[d];
    __syncthreads();
    float* hw = ws + OFF_XHW + (size_t)bd*L_;
    for (int i = 0; i < 9; ++i) {
        int p = i*256 + tid;
        int hh = p / W_, w0 = p % W_;
        float acc = bias;
        #pragma unroll
        for (int kh = 0; kh < 3; ++kh) {
            int ih = hh + kh - 1;
            if (ih < 0 || ih >= H_) continue;
            #pragma unroll
            for (int kw = 0; kw < 3; ++kw) {
                int iw = w0 + kw - 1;
                if (iw < 0 || iw >= W_) continue;
                acc = fmaf(img[ih*W_ + iw], wr[kh*3 + kw], acc);
            }
        }
        float v = acc / (1.f + __expf(-acc));
        hw[p] = v;
        res[p] = v;
    }
    __syncthreads();
    float* wh = ws + OFF_XWH + (size_t)bd*L_;
    for (int i = 0; i < 9; ++i) {
        int p = i*256 + tid;           // p = w0*H_ + hh
        int w0 = p / H_, hh = p % H_;
        wh[p] = res[hh*W_ + w0];       // stride-48 LDS read: 2-way bank alias, free
    }
}

// ---------------- K3: x_proj matvec + dt_proj + softplus + B/C split ---------
// per (b,k,ltile of 64). deltas -> (b,k,d,l); Bs/Cs -> (b,k,l,n)
__global__ __launch_bounds__(256) void k3_xproj(const float* __restrict__ xpw,
        const float* __restrict__ dtw, const float* __restrict__ dtb,
        float* __restrict__ ws) {
    __shared__ __align__(16) float Xs[48*64*4];   // xs tile [dq][l][4]
    __shared__ float xd[CD*65];                    // x_dbl tile [c][l], pad 65
    int blk = blockIdx.x;
    int b  = blk / (K_*36);
    int k  = (blk / 36) % K_;
    int l0 = (blk % 36) * 64;
    int tid = threadIdx.x;
    const float* src = ws + ((k & 1) ? OFF_XWH : OFF_XHW);
    bool flip = (k >= 2);
    for (int it = 0; it < 48; ++it) {
        int idx = it*256 + tid;
        int d = idx >> 6, l = idx & 63;
        int pos = flip ? (L_ - 1 - (l0 + l)) : (l0 + l);
        Xs[(d>>2)*256 + l*4 + (d&3)] = src[(size_t)(b*D_ + d)*L_ + pos];
    }
    __syncthreads();
    int l = tid & 63, cg = tid >> 6;
    {
        float acc[18];
        #pragma unroll
        for (int i = 0; i < 18; ++i) acc[i] = 0.f;
        for (int half = 0; half < 2; ++half) {
            float4 xr[24];
            #pragma unroll
            for (int q = 0; q < 24; ++q) xr[q] = *(const float4*)&Xs[(half*24+q)*256 + l*4];
            for (int i = 0; i < 18; ++i) {
                int c = cg*18 + i;
                if (c < CD) {
                    const float4* wp = (const float4*)(xpw + ((size_t)k*CD + c)*D_) + half*24;
                    #pragma unroll
                    for (int q = 0; q < 24; ++q) {
                        float4 wv = wp[q];
                        acc[i] += xr[q].x*wv.x + xr[q].y*wv.y + xr[q].z*wv.z + xr[q].w*wv.w;
                    }
                }
            }
        }
        for (int i = 0; i < 18; ++i) {
            int c = cg*18 + i;
            if (c < CD) xd[c*65 + l] = acc[i];
        }
    }
    __syncthreads();
    {   // dt_proj + softplus -> deltas (b,k,d,l)
        float r[6];
        #pragma unroll
        for (int rr = 0; rr < 6; ++rr) r[rr] = xd[rr*65 + l];
        float* dout = ws + OFF_DELTA + (size_t)(b*K_ + k)*D_*L_;
        int dg = tid >> 6;
        for (int i = 0; i < 48; ++i) {
            int d = dg*48 + i;
            const float* wdt = dtw + ((size_t)k*D_ + d)*6;
            float acc = dtb[k*D_ + d];
            #pragma unroll
            for (int rr = 0; rr < 6; ++rr) acc = fmaf(r[rr], wdt[rr], acc);
            float sp = fmaxf(acc, 0.f) + log1pf(__expf(-fabsf(acc)));
            dout[(size_t)d*L_ + l0 + l] = sp;
        }
    }
    {   // Bs/Cs -> (b,k,l,n)
        float* Bsp = ws + OFF_BS + ((size_t)(b*K_ + k)*L_ + l0)*NS;
        float* Csp = ws + OFF_CS + ((size_t)(b*K_ + k)*L_ + l0)*NS;
        int n = tid & 31, lq = tid >> 5;
        for (int it = 0; it < 8; ++it) {
            int ll = it*8 + lq;
            Bsp[(size_t)ll*NS + n] = xd[(RK + n)*65 + ll];
            Csp[(size_t)ll*NS + n] = xd[(RK + NS + n)*65 + ll];
        }
    }
}

// ---------------- K4a: chunked scan pass 1 — local state + chunk dA product --
// task = chain*NC + c; 32 lanes (= states) per task; 8 tasks per 256-block
__global__ __launch_bounds__(256) void k4a_local(const float* __restrict__ Alogs,
        float* __restrict__ ws) {
    int task = blockIdx.x*8 + (threadIdx.x >> 5);
    int n = threadIdx.x & 31;
    int c = task & (NC-1);
    int chain = task >> 4;             // (b*K+k)*D + d
    int d = chain % D_;
    int bk = chain / D_;
    int b = bk >> 2, k = bk & 3;
    float a = -__expf(Alogs[((size_t)k*D_ + d)*NS + n]);
    const float* dptr = ws + OFF_DELTA + (size_t)chain*L_ + c*CL;
    const float* ubase = ws + ((k & 1) ? OFF_XWH : OFF_XHW) + (size_t)(b*D_ + d)*L_;
    const float* Bsp = ws + OFF_BS + ((size_t)bk*L_ + c*CL)*NS;
    bool flip = (k >= 2);
    float h = 0.f, P = 1.f;
    #pragma unroll 4
    for (int l = 0; l < CL; ++l) {
        int gl = c*CL + l;
        float delta = dptr[l];
        float u = ubase[flip ? (L_ - 1 - gl) : gl];
        float bn = Bsp[l*NS + n];
        float dA = __expf(delta * a);
        h = fmaf(h, dA, delta*u*bn);
        P *= dA;
    }
    ws[OFF_P  + (size_t)task*NS + n] = P;
    ws[OFF_HF + (size_t)task*NS + n] = h;
}

// ---------------- K4b: per-chain serial combine over chunks ------------------
__global__ __launch_bounds__(256) void k4b_combine(float* __restrict__ ws) {
    int chain = blockIdx.x*8 + (threadIdx.x >> 5);
    int n = threadIdx.x & 31;
    size_t base = (size_t)chain*NC;
    float h0 = 0.f;
    #pragma unroll
    for (int c = 0; c < NC; ++c) {
        ws[OFF_H0 + (base + c)*NS + n] = h0;
        float P  = ws[OFF_P  + (base + c)*NS + n];
        float hF = ws[OFF_HF + (base + c)*NS + n];
        h0 = fmaf(h0, P, hF);
    }
}

// ---------------- K4c: chunked scan pass 2 — full scan + y, batched reduce ---
__global__ __launch_bounds__(256) void k4c_scan(const float* __restrict__ Alogs,
        const float* __restrict__ Dsp, float* __restrict__ ws) {
    int task = blockIdx.x*8 + (threadIdx.x >> 5);
    int n = threadIdx.x & 31;
    int c = task & (NC-1);
    int chain = task >> 4;
    int d = chain % D_;
    int bk = chain / D_;
    int b = bk >> 2, k = bk & 3;
    float a = -__expf(Alogs[((size_t)k*D_ + d)*NS + n]);
    float dcoef = Dsp[k*D_ + d];
    const float* dptr = ws + OFF_DELTA + (size_t)chain*L_ + c*CL;
    const float* ubase = ws + ((k & 1) ? OFF_XWH : OFF_XHW) + (size_t)(b*D_ + d)*L_;
    const float* Bsp = ws + OFF_BS + ((size_t)bk*L_ + c*CL)*NS;
    const float* Csp = ws + OFF_CS + ((size_t)bk*L_ + c*CL)*NS;
    float* ysp = ws + OFF_YS + ((size_t)bk*L_ + c*CL)*D_ + d;
    bool flip = (k >= 2);
    float h = ws[OFF_H0 + (size_t)task*NS + n];
    int g = n >> 3;
    int off = ((g & 1) << 1) | (g >> 1);   // lane-group -> which of the 4 l's
    for (int lb = 0; lb < CL; lb += 4) {
        float y[4], uu[4];
        #pragma unroll
        for (int j = 0; j < 4; ++j) {
            int l = lb + j;
            int gl = c*CL + l;
            float delta = dptr[l];
            float u = ubase[flip ? (L_ - 1 - gl) : gl];
            float bn = Bsp[l*NS + n];
            float cn = Csp[l*NS + n];
            float dA = __expf(delta * a);
            h = fmaf(h, dA, delta*u*bn);
            y[j] = h * cn;
            uu[j] = u;
        }
        // shared butterfly: 4 values reduced across 32 lanes
        #pragma unroll
        for (int j = 0; j < 4; ++j) y[j] += __shfl_xor(y[j], 16);
        float z0 = (n & 16) ? y[1] : y[0];
        float z1 = (n & 16) ? y[3] : y[2];
        z0 += __shfl_xor(z0, 8);
        z1 += __shfl_xor(z1, 8);
        float wv = (n & 8) ? z1 : z0;
        wv += __shfl_xor(wv, 4);
        wv += __shfl_xor(wv, 2);
        wv += __shfl_xor(wv, 1);
        // lane groups hold sums for l-offsets [0,2,1,3]
        float ua = (n & 16) ? uu[1] : uu[0];
        float ub = (n & 16) ? uu[3] : uu[2];
        float us = (n & 8) ? ub : ua;
        if ((n & 7) == 0) ysp[(size_t)(lb + off)*D_] = fmaf(dcoef, us, wv);
    }
}

// ---------------- K5: merge 4 directions + LayerNorm + SiLU(z) gate ----------
__global__ __launch_bounds__(192) void k5_combine(const float* __restrict__ lnw,
        const float* __restrict__ lnb, float* __restrict__ ws) {
    int bp = blockIdx.x;           // b*L + pos
    int b = bp / L_, pos = bp % L_;
    int d = threadIdx.x;
    int hh = pos / W_, w0 = pos % W_;
    int poswh = w0*H_ + hh;
    const float* ys = ws + OFF_YS + (size_t)b*K_*L_*D_;
    float y = ys[(size_t)(0*L_ + pos)*D_ + d]
            + ys[(size_t)(2*L_ + (L_ - 1 - pos))*D_ + d]
            + ys[(size_t)(1*L_ + poswh)*D_ + d]
            + ys[(size_t)(3*L_ + (L_ - 1 - poswh))*D_ + d];
    float s = y, ss = y*y;
    #pragma unroll
    for (int m = 32; m >= 1; m >>= 1) {
        s  += __shfl_xor(s, m);
        ss += __shfl_xor(ss, m);
    }
    __shared__ float red[2][4];
    int wv = threadIdx.x >> 6;
    if ((threadIdx.x & 63) == 0) { red[0][wv] = s; red[1][wv] = ss; }
    __syncthreads();
    float su = red[0][0] + red[0][1] + red[0][2];
    float sq = red[1][0] + red[1][1] + red[1][2];
    float mu  = su * (1.f/192.f);
    float var = sq * (1.f/192.f) - mu*mu;
    float rs  = rsqrtf(var + 1e-5f);
    float yn = (y - mu)*rs*lnw[d] + lnb[d];
    float zv = ws[OFF_Z + (size_t)(b*L_ + pos)*D_ + d];   // coalesced (b,l,d)
    float sz = zv / (1.f + __expf(-zv));
    ws[OFF_YF + (size_t)(b*L_ + pos)*D_ + d] = yn * sz;
}

// ---------------- K6: out_proj GEMM + residual (es-split x2) -----------------
__global__ __launch_bounds__(256) void k6_outproj(const float* __restrict__ w,
        const float* __restrict__ xin, float* __restrict__ out,
        const float* __restrict__ ws) {
    __shared__ __align__(16) float Ys[48*64*4];   // [dq][pos][4]
    int blk = blockIdx.x;                          // 144 = b(2) * postile(36) * es(2)
    int b = blk / 72;
    int rem = blk % 72;
    int pos0 = (rem >> 1) * 64;
    int es = rem & 1;
    int tid = threadIdx.x;
    const float* yf = ws + OFF_YF;
    for (int it = 0; it < 48; ++it) {
        int idx = it*256 + tid;
        int p = idx / 192, dd = idx % 192;
        Ys[(dd>>2)*256 + p*4 + (dd&3)] = yf[(size_t)(b*L_ + pos0 + p)*D_ + dd];
    }
    __syncthreads();
    int l = tid & 63, cg = tid >> 6;
    float acc[12];
    #pragma unroll
    for (int i = 0; i < 12; ++i) acc[i] = 0.f;
    for (int half = 0; half < 2; ++half) {
        float4 yr[24];
        #pragma unroll
        for (int q = 0; q < 24; ++q) yr[q] = *(const float4*)&Ys[(half*24+q)*256 + l*4];
        for (int i = 0; i < 12; ++i) {
            int cc = es*48 + cg*12 + i;
            const float4* wp = (const float4*)(w + (size_t)cc*D_) + half*24;
            #pragma unroll
            for (int q = 0; q < 24; ++q) {
                float4 wvv = wp[q];
                acc[i] += yr[q].x*wvv.x + yr[q].y*wvv.y + yr[q].z*wvv.z + yr[q].w*wvv.w;
            }
        }
    }
    int pos = pos0 + l;
    for (int i = 0; i < 12; ++i) {
        int cc = es*48 + cg*12 + i;
        size_t o = (size_t)(b*L_ + pos)*C_ + cc;
        out[o] = xin[o] + acc[i];
    }
}

extern "C" void kernel_launch(void* const* d_in, const int* in_sizes, int n_in,
                              void* d_out, int out_size, void* d_ws, size_t ws_size,
                              hipStream_t stream) {
    const float* x        = (const float*)d_in[0];
    const float* in_proj  = (const float*)d_in[1];
    const float* conv_w   = (const float*)d_in[2];
    const float* conv_b   = (const float*)d_in[3];
    const float* x_proj_w = (const float*)d_in[4];
    const float* dt_w     = (const float*)d_in[5];
    const float* dt_b     = (const float*)d_in[6];
    const float* A_logs   = (const float*)d_in[7];
    const float* Ds       = (const float*)d_in[8];
    const float* ln_w     = (const float*)d_in[9];
    const float* ln_b     = (const float*)d_in[10];
    const float* out_w    = (const float*)d_in[11];
    float* out = (float*)d_out;
    float* ws  = (float*)d_ws;

    k1_inproj  <<<288,        256, 0, stream>>>(x, in_proj, ws);
    k2_conv    <<<B_*D_,      256, 0, stream>>>(conv_w, conv_b, ws);
    k3_xproj   <<<288,        256, 0, stream>>>(x_proj_w, dt_w, dt_b, ws);
    k4a_local  <<<NCH*NC/8,   256, 0, stream>>>(A_logs, ws);
    k4b_combine<<<NCH/8,      256, 0, stream>>>(ws);
    k4c_scan   <<<NCH*NC/8,   256, 0, stream>>>(A_logs, Ds, ws);
    k5_combine <<<B_*L_,      192, 0, stream>>>(ln_w, ln_b, ws);
    k6_outproj <<<144,        256, 0, stream>>>(out_w, x, out, ws);
}

// Round 4
// 284.174 us; speedup vs baseline: 5.1561x; 1.3116x over previous
//
#include <hip/hip_runtime.h>
#include <math.h>

#define B_ 2
#define H_ 48
#define W_ 48
#define C_ 96
#define D_ 192
#define L_ 2304   // H_*W_
#define K_ 4
#define NS 32     // D_STATE
#define RK 6      // DT_RANK
#define CD 70     // RK + 2*NS

#define NC 16         // scan chunks
#define CL (L_/NC)    // 144 steps per chunk
#define NCH (B_*K_*D_)// 1536 chains

// workspace offsets (floats)
#define BDL (B_*D_*L_)                    // 884736
#define OFF_Z      0                      // z stored (b, l, d)
#define OFF_XPRE   (OFF_Z    + BDL)
#define OFF_XHW    (OFF_XPRE + BDL)
#define OFF_XWH    (OFF_XHW  + BDL)
#define OFF_DELTA  (OFF_XWH  + BDL)      // size B*K*D*L, layout (b,k,d,l)
#define OFF_BS     (OFF_DELTA+ B_*K_*D_*L_)  // (b,k,l,n)
#define OFF_CS     (OFF_BS   + B_*K_*L_*NS)
#define OFF_YS     (OFF_CS   + B_*K_*L_*NS)  // (b,k,l,d)
#define OFF_YF     (OFF_YS   + B_*K_*L_*D_)  // B*L*D

// H0 scratch: NCH*NC*NS = 786432 floats <= YF region (884736); k4c consumes
// H0 before k5 writes YF.
#define OFF_H0     OFF_YF

// ---------------- K1: in_proj GEMM ------------------------------------------
// grid 576 = b(2) * ltile32(72) * es(4); es 0,1 -> xpre (b,d,pos); 2,3 -> z (b,l,d)
__global__ __launch_bounds__(256) void k1_inproj(const float* __restrict__ x,
        const float* __restrict__ w, float* __restrict__ ws) {
    __shared__ __align__(16) float Xs[24*128];   // [cq][l*4+sub], 32 l
    int blk = blockIdx.x;
    int b = blk / 288;
    int rem = blk % 288;
    int l0 = (rem >> 2) * 32;
    int es = rem & 3;
    int tid = threadIdx.x;
    const float4* xs4 = (const float4*)(x + (size_t)(b*L_ + l0)*C_);
    #pragma unroll
    for (int it = 0; it < 3; ++it) {
        int i4 = it*256 + tid;        // 768 float4 = 3072 floats
        float4 v = xs4[i4];
        int idx4 = i4*4;
        int p = idx4 / 96, c = idx4 % 96;   // c % 4 == 0
        *(float4*)&Xs[(c>>2)*128 + p*4] = v;
    }
    __syncthreads();
    int l = tid & 31, eg = tid >> 5;
    int pos = l0 + l;
    float acc[12];
    #pragma unroll
    for (int i = 0; i < 12; ++i) acc[i] = 0.f;
    const float4* wp[12];
    #pragma unroll
    for (int i = 0; i < 12; ++i) {
        int e = es*96 + eg*12 + i;
        wp[i] = (const float4*)(w + (size_t)e*96);
    }
    for (int q = 0; q < 24; ++q) {
        float4 xr = *(const float4*)&Xs[q*128 + l*4];
        #pragma unroll
        for (int i = 0; i < 12; ++i) {
            float4 wv = wp[i][q];
            acc[i] += xr.x*wv.x + xr.y*wv.y + xr.z*wv.z + xr.w*wv.w;
        }
    }
    if (es < 2) {
        float* xpre = ws + OFF_XPRE;
        #pragma unroll
        for (int i = 0; i < 12; ++i) {
            int e = es*96 + eg*12 + i;
            xpre[(size_t)(b*D_ + e)*L_ + pos] = acc[i];
        }
    } else {
        float* zp = ws + OFF_Z + (size_t)(b*L_ + pos)*D_ + (es-2)*96 + eg*12;
        #pragma unroll
        for (int q = 0; q < 3; ++q)
            *(float4*)&zp[q*4] = make_float4(acc[q*4], acc[q*4+1], acc[q*4+2], acc[q*4+3]);
    }
}

// ---------------- K2: depthwise 3x3 conv + SiLU, half-image blocks ----------
__global__ __launch_bounds__(256) void k2_conv(const float* __restrict__ cw,
        const float* __restrict__ cb, float* __restrict__ ws) {
    __shared__ float img[26*48];
    __shared__ float res[24*49];     // padded for transpose read
    int blk = blockIdx.x;            // 768 = bd*2 + half
    int bd = blk >> 1;
    int half = blk & 1;
    int d = bd % D_;
    int hh0 = half * 24;
    int tid = threadIdx.x;
    const float* xp = ws + OFF_XPRE + (size_t)bd*L_;
    for (int it = 0; it < 5; ++it) {
        int idx = it*256 + tid;
        if (idx < 26*48) {
            int gr = hh0 - 1 + idx/48;
            img[idx] = (gr >= 0 && gr < H_) ? xp[gr*48 + idx%48] : 0.f;
        }
    }
    float wr[9];
    #pragma unroll
    for (int j = 0; j < 9; ++j) wr[j] = cw[d*9 + j];
    float bias = cb[d];
    __syncthreads();
    float* hw = ws + OFF_XHW + (size_t)bd*L_ + hh0*48;
    for (int it = 0; it < 5; ++it) {
        int idx = it*256 + tid;
        if (idx < 24*48) {
            int r = idx/48, w0 = idx%48;
            float acc = bias;
            #pragma unroll
            for (int kh = 0; kh < 3; ++kh) {
                #pragma unroll
                for (int kw = 0; kw < 3; ++kw) {
                    int iw = w0 + kw - 1;
                    if (iw >= 0 && iw < W_)
                        acc = fmaf(img[(r+kh)*48 + iw], wr[kh*3 + kw], acc);
                }
            }
            float v = acc / (1.f + __expf(-acc));
            hw[idx] = v;
            res[r*49 + w0] = v;
        }
    }
    __syncthreads();
    float* wh = ws + OFF_XWH + (size_t)bd*L_;
    for (int it = 0; it < 5; ++it) {
        int idx = it*256 + tid;
        if (idx < 24*48) {
            int w0 = idx/24, r = idx%24;
            wh[w0*48 + hh0 + r] = res[r*49 + w0];
        }
    }
}

// ---------------- K3: x_proj matvec + dt_proj + softplus + B/C split --------
// grid 1152 = b(2) * k(4) * ltile16(144)
__global__ __launch_bounds__(256) void k3_xproj(const float* __restrict__ xpw,
        const float* __restrict__ dtw, const float* __restrict__ dtb,
        float* __restrict__ ws) {
    __shared__ __align__(16) float Xs[48*64];    // [dq][l*4+sub], 16 l
    __shared__ float xd[CD*17];                  // [c][l], pad 17
    int blk = blockIdx.x;
    int b = blk / 576;
    int rem = blk % 576;
    int k = rem / 144;
    int l0 = (rem % 144) * 16;
    int tid = threadIdx.x;
    const float* src = ws + ((k & 1) ? OFF_XWH : OFF_XHW);
    bool flip = (k >= 2);
    #pragma unroll
    for (int it = 0; it < 12; ++it) {
        int idx = it*256 + tid;
        int d = idx >> 4, l = idx & 15;
        int pos = flip ? (L_ - 1 - (l0 + l)) : (l0 + l);
        Xs[(d>>2)*64 + l*4 + (d&3)] = src[(size_t)(b*D_ + d)*L_ + pos];
    }
    __syncthreads();
    int l = tid & 15, cg = tid >> 4;    // 16 l x 16 cg
    {
        float acc[5] = {0.f, 0.f, 0.f, 0.f, 0.f};
        const float4* wp[5];
        #pragma unroll
        for (int i = 0; i < 5; ++i) {
            int c = cg + 16*i;
            if (c >= CD) c = 0;          // guard OOB; result masked on write
            wp[i] = (const float4*)(xpw + ((size_t)k*CD + c)*D_);
        }
        for (int q = 0; q < 48; ++q) {
            float4 xr = *(const float4*)&Xs[q*64 + l*4];
            #pragma unroll
            for (int i = 0; i < 5; ++i) {
                float4 wv = wp[i][q];
                acc[i] += xr.x*wv.x + xr.y*wv.y + xr.z*wv.z + xr.w*wv.w;
            }
        }
        #pragma unroll
        for (int i = 0; i < 5; ++i) {
            int c = cg + 16*i;
            if (c < CD) xd[c*17 + l] = acc[i];
        }
    }
    __syncthreads();
    {   // dt_proj + softplus -> deltas (b,k,d,l)
        float r[6];
        #pragma unroll
        for (int rr = 0; rr < 6; ++rr) r[rr] = xd[rr*17 + l];
        float* dout = ws + OFF_DELTA + (size_t)(b*K_ + k)*D_*L_;
        int dg = tid >> 4;
        for (int i = 0; i < 12; ++i) {
            int d = dg*12 + i;
            const float* wdt = dtw + ((size_t)k*D_ + d)*6;
            float acc = dtb[k*D_ + d];
            #pragma unroll
            for (int rr = 0; rr < 6; ++rr) acc = fmaf(r[rr], wdt[rr], acc);
            float sp = fmaxf(acc, 0.f) + log1pf(__expf(-fabsf(acc)));
            dout[(size_t)d*L_ + l0 + l] = sp;
        }
    }
    {   // Bs/Cs -> (b,k,l,n)
        float* Bsp = ws + OFF_BS + ((size_t)(b*K_ + k)*L_ + l0)*NS;
        float* Csp = ws + OFF_CS + ((size_t)(b*K_ + k)*L_ + l0)*NS;
        int n = tid & 31, lq = tid >> 5;
        #pragma unroll
        for (int j = 0; j < 2; ++j) {
            int ll = lq + 8*j;
            Bsp[(size_t)ll*NS + n] = xd[(RK + n)*17 + ll];
            Csp[(size_t)ll*NS + n] = xd[(RK + NS + n)*17 + ll];
        }
    }
}

// ---------------- K4a: local chunk scan + in-LDS combine -> H0 --------------
// block = (bk, d-pair); 512 threads = 16 chunks x 32 states; 2 chains/lane
__global__ __launch_bounds__(512) void k4a_local(const float* __restrict__ Alogs,
        float* __restrict__ ws) {
    __shared__ float Pl[2][NC][NS];
    __shared__ float Hl[2][NC][NS];
    int blk = blockIdx.x;            // 768 = bk(8) * pair(96)
    int bk = blk / 96;
    int p = blk % 96;
    int b = bk >> 2, k = bk & 3;
    int c = threadIdx.x >> 5;
    int n = threadIdx.x & 31;
    int dA = 2*p;
    float aA = -__expf(Alogs[((size_t)k*D_ + dA)*NS + n]);
    float aB = -__expf(Alogs[((size_t)k*D_ + dA + 1)*NS + n]);
    const float* dpA = ws + OFF_DELTA + (size_t)(bk*D_ + dA)*L_ + c*CL;
    const float* dpB = dpA + L_;
    const float* uA = ws + ((k & 1) ? OFF_XWH : OFF_XHW) + (size_t)(b*D_ + dA)*L_;
    const float* uB = uA + L_;
    const float* Bsp = ws + OFF_BS + ((size_t)bk*L_ + c*CL)*NS;
    bool flip = (k >= 2);
    float hA = 0.f, hB = 0.f, PA = 1.f, PB = 1.f;
    #pragma unroll 4
    for (int l = 0; l < CL; ++l) {
        int gl = c*CL + l;
        int gu = flip ? (L_ - 1 - gl) : gl;
        float dlA = dpA[l], dlB = dpB[l];
        float uAv = uA[gu], uBv = uB[gu];
        float bn = Bsp[l*NS + n];
        float eA = __expf(dlA * aA);
        float eB = __expf(dlB * aB);
        hA = fmaf(hA, eA, dlA*uAv*bn);
        hB = fmaf(hB, eB, dlB*uBv*bn);
        PA *= eA;
        PB *= eB;
    }
    Pl[0][c][n] = PA; Pl[1][c][n] = PB;
    Hl[0][c][n] = hA; Hl[1][c][n] = hB;
    __syncthreads();
    if (threadIdx.x < 64) {
        int ch = threadIdx.x >> 5, nn = threadIdx.x & 31;
        float* H0p = ws + OFF_H0 + (size_t)(bk*D_ + dA + ch)*NC*NS + nn;
        float h = 0.f;
        #pragma unroll
        for (int cc = 0; cc < NC; ++cc) {
            H0p[cc*NS] = h;
            h = fmaf(h, Pl[ch][cc][nn], Hl[ch][cc][nn]);
        }
    }
}

// ---------------- K4c: replay with true h0; y staged in LDS, coalesced write
// block = (bk, chunk, 32-d group); 512 threads = 16 subwaves x 2 chains
__global__ __launch_bounds__(512) void k4c_scan(const float* __restrict__ Alogs,
        const float* __restrict__ Dsp, float* __restrict__ ws) {
    __shared__ float yld[CL*32];     // [l][dd] 18.4KB
    int blk = blockIdx.x;            // 768 = bk(8) * c(16) * dg(6)
    int dg = blk % 6;
    int c  = (blk / 6) % NC;
    int bk = blk / (6*NC);
    int b = bk >> 2, k = bk & 3;
    int sw = threadIdx.x >> 5;
    int n  = threadIdx.x & 31;
    int dA = dg*32 + sw;
    int dB = dA + 16;
    float aA = -__expf(Alogs[((size_t)k*D_ + dA)*NS + n]);
    float aB = -__expf(Alogs[((size_t)k*D_ + dB)*NS + n]);
    float dcA = Dsp[k*D_ + dA];
    float dcB = Dsp[k*D_ + dB];
    const float* dpA = ws + OFF_DELTA + (size_t)(bk*D_ + dA)*L_ + c*CL;
    const float* dpB = dpA + 16*L_;
    const float* uA = ws + ((k & 1) ? OFF_XWH : OFF_XHW) + (size_t)(b*D_ + dA)*L_;
    const float* uB = uA + 16*L_;
    const float* Bsp = ws + OFF_BS + ((size_t)bk*L_ + c*CL)*NS;
    const float* Csp = ws + OFF_CS + ((size_t)bk*L_ + c*CL)*NS;
    bool flip = (k >= 2);
    float hA = ws[OFF_H0 + (size_t)(bk*D_ + dA)*NC*NS + c*NS + n];
    float hB = ws[OFF_H0 + (size_t)(bk*D_ + dB)*NC*NS + c*NS + n];
    int g = n >> 3;
    int off = ((g & 1) << 1) | (g >> 1);
    for (int lb = 0; lb < CL; lb += 4) {
        float yA[4], yB[4], uuA[4], uuB[4];
        #pragma unroll
        for (int j = 0; j < 4; ++j) {
            int l = lb + j;
            int gl = c*CL + l;
            int gu = flip ? (L_ - 1 - gl) : gl;
            float dlA = dpA[l], dlB = dpB[l];
            float uAv = uA[gu], uBv = uB[gu];
            float bn = Bsp[l*NS + n];
            float cn = Csp[l*NS + n];
            hA = fmaf(hA, __expf(dlA*aA), dlA*uAv*bn);
            hB = fmaf(hB, __expf(dlB*aB), dlB*uBv*bn);
            yA[j] = hA * cn; yB[j] = hB * cn;
            uuA[j] = uAv;    uuB[j] = uBv;
        }
        #pragma unroll
        for (int j = 0; j < 4; ++j) {
            yA[j] += __shfl_xor(yA[j], 16);
            yB[j] += __shfl_xor(yB[j], 16);
        }
        float zA0 = (n & 16) ? yA[1] : yA[0];
        float zA1 = (n & 16) ? yA[3] : yA[2];
        float zB0 = (n & 16) ? yB[1] : yB[0];
        float zB1 = (n & 16) ? yB[3] : yB[2];
        zA0 += __shfl_xor(zA0, 8); zA1 += __shfl_xor(zA1, 8);
        zB0 += __shfl_xor(zB0, 8); zB1 += __shfl_xor(zB1, 8);
        float wA = (n & 8) ? zA1 : zA0;
        float wB = (n & 8) ? zB1 : zB0;
        wA += __shfl_xor(wA, 4); wA += __shfl_xor(wA, 2); wA += __shfl_xor(wA, 1);
        wB += __shfl_xor(wB, 4); wB += __shfl_xor(wB, 2); wB += __shfl_xor(wB, 1);
        float uaA = (n & 16) ? uuA[1] : uuA[0];
        float ubA = (n & 16) ? uuA[3] : uuA[2];
        float usA = (n & 8) ? ubA : uaA;
        float uaB = (n & 16) ? uuB[1] : uuB[0];
        float ubB = (n & 16) ? uuB[3] : uuB[2];
        float usB = (n & 8) ? ubB : uaB;
        if ((n & 7) == 0) {
            yld[(lb + off)*32 + sw]      = fmaf(dcA, usA, wA);
            yld[(lb + off)*32 + sw + 16] = fmaf(dcB, usB, wB);
        }
    }
    __syncthreads();
    float* ysp = ws + OFF_YS + ((size_t)bk*L_ + c*CL)*D_ + dg*32;
    #pragma unroll
    for (int it = 0; it < 9; ++it) {
        int idx = it*512 + threadIdx.x;
        int l = idx >> 5, dd = idx & 31;
        ysp[(size_t)l*D_ + dd] = yld[idx];
    }
}

// ---------------- K5: merge 4 directions + LayerNorm + SiLU(z) gate ---------
__global__ __launch_bounds__(192) void k5_combine(const float* __restrict__ lnw,
        const float* __restrict__ lnb, float* __restrict__ ws) {
    int bp = blockIdx.x;
    int b = bp / L_, pos = bp % L_;
    int d = threadIdx.x;
    int hh = pos / W_, w0 = pos % W_;
    int poswh = w0*H_ + hh;
    const float* ys = ws + OFF_YS + (size_t)b*K_*L_*D_;
    float y = ys[(size_t)(0*L_ + pos)*D_ + d]
            + ys[(size_t)(2*L_ + (L_ - 1 - pos))*D_ + d]
            + ys[(size_t)(1*L_ + poswh)*D_ + d]
            + ys[(size_t)(3*L_ + (L_ - 1 - poswh))*D_ + d];
    float s = y, ss = y*y;
    #pragma unroll
    for (int m = 32; m >= 1; m >>= 1) {
        s  += __shfl_xor(s, m);
        ss += __shfl_xor(ss, m);
    }
    __shared__ float red[2][4];
    int wv = threadIdx.x >> 6;
    if ((threadIdx.x & 63) == 0) { red[0][wv] = s; red[1][wv] = ss; }
    __syncthreads();
    float su = red[0][0] + red[0][1] + red[0][2];
    float sq = red[1][0] + red[1][1] + red[1][2];
    float mu  = su * (1.f/192.f);
    float var = sq * (1.f/192.f) - mu*mu;
    float rs  = rsqrtf(var + 1e-5f);
    float yn = (y - mu)*rs*lnw[d] + lnb[d];
    float zv = ws[OFF_Z + (size_t)(b*L_ + pos)*D_ + d];
    float sz = zv / (1.f + __expf(-zv));
    ws[OFF_YF + (size_t)(b*L_ + pos)*D_ + d] = yn * sz;
}

// ---------------- K6: out_proj GEMM + residual ------------------------------
// grid 576 = b(2) * ltile16(144) * es(2); LDS-staged coalesced epilogue
__global__ __launch_bounds__(256) void k6_outproj(const float* __restrict__ w,
        const float* __restrict__ xin, float* __restrict__ out,
        const float* __restrict__ ws) {
    __shared__ __align__(16) float Ys[48*64];    // [dq][l*4+sub], 16 l
    __shared__ float outT[16*49];
    int blk = blockIdx.x;
    int b = blk / 288;
    int rem = blk % 288;
    int l0 = (rem >> 1) * 16;
    int es = rem & 1;
    int tid = threadIdx.x;
    const float4* yf4 = (const float4*)(ws + OFF_YF + (size_t)(b*L_ + l0)*D_);
    #pragma unroll
    for (int it = 0; it < 3; ++it) {
        int i4 = it*256 + tid;        // 768 float4 = 3072 floats
        float4 v = yf4[i4];
        int idx4 = i4*4;
        int p = idx4 / 192, dd = idx4 % 192;
        *(float4*)&Ys[(dd>>2)*64 + p*4] = v;
    }
    __syncthreads();
    int l = tid & 15, cg = tid >> 4;
    float acc[3] = {0.f, 0.f, 0.f};
    const float4* wp[3];
    #pragma unroll
    for (int i = 0; i < 3; ++i) {
        int c = es*48 + cg*3 + i;
        wp[i] = (const float4*)(w + (size_t)c*D_);
    }
    for (int q = 0; q < 48; ++q) {
        float4 xr = *(const float4*)&Ys[q*64 + l*4];
        #pragma unroll
        for (int i = 0; i < 3; ++i) {
            float4 wv = wp[i][q];
            acc[i] += xr.x*wv.x + xr.y*wv.y + xr.z*wv.z + xr.w*wv.w;
        }
    }
    #pragma unroll
    for (int i = 0; i < 3; ++i) outT[l*49 + cg*3 + i] = acc[i];
    __syncthreads();
    #pragma unroll
    for (int it = 0; it < 3; ++it) {
        int idx = it*256 + tid;       // 768 outputs
        int p = idx / 48, cc = idx % 48;
        size_t o = (size_t)(b*L_ + l0 + p)*C_ + es*48 + cc;
        out[o] = xin[o] + outT[p*49 + cc];
    }
}

extern "C" void kernel_launch(void* const* d_in, const int* in_sizes, int n_in,
                              void* d_out, int out_size, void* d_ws, size_t ws_size,
                              hipStream_t stream) {
    const float* x        = (const float*)d_in[0];
    const float* in_proj  = (const float*)d_in[1];
    const float* conv_w   = (const float*)d_in[2];
    const float* conv_b   = (const float*)d_in[3];
    const float* x_proj_w = (const float*)d_in[4];
    const float* dt_w     = (const float*)d_in[5];
    const float* dt_b     = (const float*)d_in[6];
    const float* A_logs   = (const float*)d_in[7];
    const float* Ds       = (const float*)d_in[8];
    const float* ln_w     = (const float*)d_in[9];
    const float* ln_b     = (const float*)d_in[10];
    const float* out_w    = (const float*)d_in[11];
    float* out = (float*)d_out;
    float* ws  = (float*)d_ws;

    k1_inproj <<<576,  256, 0, stream>>>(x, in_proj, ws);
    k2_conv   <<<768,  256, 0, stream>>>(conv_w, conv_b, ws);
    k3_xproj  <<<1152, 256, 0, stream>>>(x_proj_w, dt_w, dt_b, ws);
    k4a_local <<<768,  512, 0, stream>>>(A_logs, ws);
    k4c_scan  <<<768,  512, 0, stream>>>(A_logs, Ds, ws);
    k5_combine<<<B_*L_,192, 0, stream>>>(ln_w, ln_b, ws);
    k6_outproj<<<576,  256, 0, stream>>>(out_w, x, out, ws);
}